// Round 1
// baseline (2264.211 us; speedup 1.0000x reference)
//
#include <hip/hip_runtime.h>
#include <stdint.h>

#define M_TOK 8192   // B*T
#define DDIM  2048
#define HDIM  4096
#define NEXP  16
#define ODIM  2048

typedef __attribute__((ext_vector_type(8))) __bf16 bf16x8;
typedef __attribute__((ext_vector_type(4))) float  f32x4;

__device__ __forceinline__ unsigned short f2bf(float f) {
    unsigned int u = __float_as_uint(f);
    unsigned int r = (u + 0x7FFFu + ((u >> 16) & 1u)) >> 16;   // RNE
    return (unsigned short)r;
}
__device__ __forceinline__ float bf2f(unsigned short s) {
    return __uint_as_float(((unsigned int)s) << 16);
}

// ---------------- preprocessing ----------------

// x fp32 -> x_hi, x_lo bf16 (split precision for router; x_hi reused by experts)
__global__ void split_x_kernel(const float* __restrict__ x,
                               ushort* __restrict__ xh, ushort* __restrict__ xl) {
    size_t i = ((size_t)blockIdx.x * 256 + threadIdx.x) * 4;
    float4 v = *(const float4*)(x + i);
    float f[4] = {v.x, v.y, v.z, v.w};
    ushort hu[4], lu[4];
#pragma unroll
    for (int u = 0; u < 4; ++u) {
        hu[u] = f2bf(f[u]);
        lu[u] = f2bf(f[u] - bf2f(hu[u]));
    }
    *(ushort4*)(xh + i) = make_ushort4(hu[0], hu[1], hu[2], hu[3]);
    *(ushort4*)(xl + i) = make_ushort4(lu[0], lu[1], lu[2], lu[3]);
}

// W1 [D,H] fp32 -> W1^T hi/lo bf16 [H,D]
__global__ void transpose_split_w1_kernel(const float* __restrict__ W1,
                                          ushort* __restrict__ th, ushort* __restrict__ tl) {
    __shared__ float tile[64][65];
    int h0 = (blockIdx.x & 63) * 64;          // 64 h-tiles
    int d0 = (blockIdx.x >> 6) * 64;          // 32 d-tiles
    int r = threadIdx.x >> 4;
    int c = (threadIdx.x & 15) * 4;
#pragma unroll
    for (int rr = 0; rr < 4; ++rr) {
        int row = rr * 16 + r;
        float4 v = *(const float4*)(W1 + (size_t)(d0 + row) * HDIM + h0 + c);
        tile[row][c + 0] = v.x; tile[row][c + 1] = v.y;
        tile[row][c + 2] = v.z; tile[row][c + 3] = v.w;
    }
    __syncthreads();
#pragma unroll
    for (int rr = 0; rr < 4; ++rr) {
        int hrow = rr * 16 + r;
        ushort hu[4], lu[4];
#pragma unroll
        for (int u = 0; u < 4; ++u) {
            float f = tile[c + u][hrow];
            hu[u] = f2bf(f);
            lu[u] = f2bf(f - bf2f(hu[u]));
        }
        size_t o = (size_t)(h0 + hrow) * DDIM + d0 + c;
        *(ushort4*)(th + o) = make_ushort4(hu[0], hu[1], hu[2], hu[3]);
        *(ushort4*)(tl + o) = make_ushort4(lu[0], lu[1], lu[2], lu[3]);
    }
}

// We [E,D,O] fp32 -> We^T bf16 [E,O,D]
__global__ void transpose_we_kernel(const float* __restrict__ We, ushort* __restrict__ wt) {
    __shared__ float tile[64][65];
    int e = blockIdx.y;
    int o0 = (blockIdx.x & 31) * 64;
    int d0 = (blockIdx.x >> 5) * 64;
    const float* src = We + (size_t)e * DDIM * ODIM;
    ushort* dst = wt + (size_t)e * ODIM * DDIM;
    int r = threadIdx.x >> 4;
    int c = (threadIdx.x & 15) * 4;
#pragma unroll
    for (int rr = 0; rr < 4; ++rr) {
        int row = rr * 16 + r;
        float4 v = *(const float4*)(src + (size_t)(d0 + row) * ODIM + o0 + c);
        tile[row][c + 0] = v.x; tile[row][c + 1] = v.y;
        tile[row][c + 2] = v.z; tile[row][c + 3] = v.w;
    }
    __syncthreads();
#pragma unroll
    for (int rr = 0; rr < 4; ++rr) {
        int orow = rr * 16 + r;
        ushort hu[4];
#pragma unroll
        for (int u = 0; u < 4; ++u) hu[u] = f2bf(tile[c + u][orow]);
        *(ushort4*)(dst + (size_t)(o0 + orow) * DDIM + d0 + c) =
            make_ushort4(hu[0], hu[1], hu[2], hu[3]);
    }
}

// ---------------- GEMM core (128x128 tile, BK=64, xor-swizzled LDS) ----------------
// LDS tile: 1024 slots of 16B. slot(m, kc) = m*8 + (kc ^ (m&7)); kc = 8-elem chunk of k.
// global_load_lds width=16: lds dest is wave-uniform base + lane*16, so we permute the
// GLOBAL address per lane to realize the swizzle (guide §5 caveat).

__device__ __forceinline__ void stage_tile(const ushort* __restrict__ g0, int ld,
                                           ushort* lds0, int wave, int lane) {
#pragma unroll
    for (int j = 0; j < 4; ++j) {
        int L = wave * 256 + j * 64 + lane;
        int m = L >> 3;
        int kc = (L & 7) ^ (m & 7);
        const ushort* gp = g0 + (size_t)m * ld + kc * 8;
        ushort* lp = lds0 + (size_t)(wave * 256 + j * 64) * 8;
        __builtin_amdgcn_global_load_lds(
            (const __attribute__((address_space(1))) void*)gp,
            (__attribute__((address_space(3))) void*)lp, 16, 0, 0);
    }
}

__device__ __forceinline__ bf16x8 ldfrag(const ushort* lds0, int row, int kc) {
    return *(const bf16x8*)(lds0 + ((row << 3) + (kc ^ (row & 7))) * 8);
}

// Router GEMM1: h = relu([x_hi|x_lo|x_hi] @ [W1hi|W1hi|W1lo]^T + b1), K=3*2048
__global__ __launch_bounds__(256, 2) void gemm1_kernel(
    const ushort* __restrict__ xh, const ushort* __restrict__ xl,
    const ushort* __restrict__ wh, const ushort* __restrict__ wl,
    const float* __restrict__ b1, float* __restrict__ hout) {
    __shared__ ushort As[8192];
    __shared__ ushort Bs[8192];
    const int tile_m = (blockIdx.x & 63) << 7;
    const int tile_n = (blockIdx.x >> 6) << 7;
    const int tid = threadIdx.x;
    const int wave = tid >> 6, lane = tid & 63;
    const int q = lane >> 4, mrow = lane & 15;
    const int wm = (wave >> 1) << 6, wn = (wave & 1) << 6;
    f32x4 acc[4][4];
#pragma unroll
    for (int i = 0; i < 4; ++i)
#pragma unroll
        for (int j = 0; j < 4; ++j) acc[i][j] = {0.f, 0.f, 0.f, 0.f};

    for (int it = 0; it < 96; ++it) {
        const int phase = it >> 5;
        const ushort* Ab = (phase == 1) ? xl : xh;
        const ushort* Bb = (phase == 2) ? wl : wh;
        const int k0 = (it & 31) << 6;
        __syncthreads();
        stage_tile(Ab + (size_t)tile_m * DDIM + k0, DDIM, As, wave, lane);
        stage_tile(Bb + (size_t)tile_n * DDIM + k0, DDIM, Bs, wave, lane);
        __syncthreads();
#pragma unroll
        for (int s = 0; s < 2; ++s) {
            bf16x8 af[4], bfr[4];
#pragma unroll
            for (int i = 0; i < 4; ++i) af[i] = ldfrag(As, wm + i * 16 + mrow, s * 4 + q);
#pragma unroll
            for (int j = 0; j < 4; ++j) bfr[j] = ldfrag(Bs, wn + j * 16 + mrow, s * 4 + q);
#pragma unroll
            for (int i = 0; i < 4; ++i)
#pragma unroll
                for (int j = 0; j < 4; ++j)
                    acc[i][j] = __builtin_amdgcn_mfma_f32_16x16x32_bf16(
                        af[i], bfr[j], acc[i][j], 0, 0, 0);
        }
    }
#pragma unroll
    for (int i = 0; i < 4; ++i) {
        const int r0 = tile_m + wm + i * 16 + q * 4;
#pragma unroll
        for (int j = 0; j < 4; ++j) {
            const int cc = tile_n + wn + j * 16 + mrow;
            const float bb = b1[cc];
#pragma unroll
            for (int r = 0; r < 4; ++r) {
                float v = acc[i][j][r] + bb;
                hout[(size_t)(r0 + r) * HDIM + cc] = v > 0.f ? v : 0.f;
            }
        }
    }
}

// GEMM2 (fp32 vector): logits = h @ W2 + b2.  16 tokens x 16 experts per block.
__global__ void gemm2_kernel(const float* __restrict__ h, const float* __restrict__ W2,
                             const float* __restrict__ b2, float* __restrict__ logits) {
    const int e = threadIdx.x & 15;
    const int t = blockIdx.x * 16 + (threadIdx.x >> 4);
    const float* hr = h + (size_t)t * HDIM;
    float acc = 0.f;
    for (int d = 0; d < HDIM; d += 8) {
#pragma unroll
        for (int u = 0; u < 8; ++u)
            acc = fmaf(hr[d + u], W2[(size_t)(d + u) * NEXP + e], acc);
    }
    logits[(size_t)t * NEXP + e] = acc + b2[e];
}

// softmax -> mask -> gates, k_per_token (as float, matching harness fp32 readback)
__global__ void gates_kernel(const float* __restrict__ logits,
                             float* __restrict__ gates, float* __restrict__ kout) {
    const int t = blockIdx.x * 256 + threadIdx.x;
    float l[16];
    const float4* lp = (const float4*)(logits + (size_t)t * 16);
#pragma unroll
    for (int i = 0; i < 4; ++i) {
        float4 v = lp[i];
        l[i * 4] = v.x; l[i * 4 + 1] = v.y; l[i * 4 + 2] = v.z; l[i * 4 + 3] = v.w;
    }
    float lmax = l[0];
#pragma unroll
    for (int i = 1; i < 16; ++i) lmax = fmaxf(lmax, l[i]);
    float p[16], S = 0.f;
#pragma unroll
    for (int i = 0; i < 16; ++i) { p[i] = expf(l[i] - lmax); S += p[i]; }
#pragma unroll
    for (int i = 0; i < 16; ++i) p[i] /= S;
    float pmax = p[0];
#pragma unroll
    for (int i = 1; i < 16; ++i) pmax = fmaxf(pmax, p[i]);
    const float thr = 0.5f * pmax;
    int k = 0;
    float g[16];
#pragma unroll
    for (int i = 0; i < 16; ++i) {
        bool m = p[i] >= thr;
        g[i] = m ? p[i] : 0.f;
        k += m ? 1 : 0;
    }
    float4* gp = (float4*)(gates + (size_t)t * 16);
#pragma unroll
    for (int i = 0; i < 4; ++i)
        gp[i] = make_float4(g[i * 4], g[i * 4 + 1], g[i * 4 + 2], g[i * 4 + 3]);
    kout[t] = (float)k;
}

// Fused expert GEMM: out = sum_i gates_i * (x @ We_i + be_i).
// K = E*D = 32768; per-expert accumulator flush every 32 iters scales by gate.
__global__ __launch_bounds__(256, 2) void moe_gemm_kernel(
    const ushort* __restrict__ xh, const ushort* __restrict__ weT,
    const float* __restrict__ gates, const float* __restrict__ be,
    float* __restrict__ out) {
    __shared__ ushort As[8192];
    __shared__ ushort Bs[8192];
    __shared__ float gs[2048];   // gates for this block's 128 rows x 16 experts
    const int tile_m = (blockIdx.x & 63) << 7;
    const int tile_n = (blockIdx.x >> 6) << 7;
    const int tid = threadIdx.x;
    const int wave = tid >> 6, lane = tid & 63;
    const int q = lane >> 4, mrow = lane & 15;
    const int wm = (wave >> 1) << 6, wn = (wave & 1) << 6;
    for (int i = tid; i < 2048; i += 256) gs[i] = gates[(size_t)tile_m * NEXP + i];
    f32x4 acc[4][4], eacc[4][4];
#pragma unroll
    for (int i = 0; i < 4; ++i)
#pragma unroll
        for (int j = 0; j < 4; ++j) { acc[i][j] = {0.f, 0.f, 0.f, 0.f}; eacc[i][j] = {0.f, 0.f, 0.f, 0.f}; }

    for (int it = 0; it < 512; ++it) {
        const int k0 = (it & 31) << 6;
        const size_t ex = (size_t)(it >> 5);
        __syncthreads();
        stage_tile(xh + (size_t)tile_m * DDIM + k0, DDIM, As, wave, lane);
        stage_tile(weT + ex * ((size_t)ODIM * DDIM) + (size_t)tile_n * DDIM + k0,
                   DDIM, Bs, wave, lane);
        __syncthreads();
#pragma unroll
        for (int s = 0; s < 2; ++s) {
            bf16x8 af[4], bfr[4];
#pragma unroll
            for (int i = 0; i < 4; ++i) af[i] = ldfrag(As, wm + i * 16 + mrow, s * 4 + q);
#pragma unroll
            for (int j = 0; j < 4; ++j) bfr[j] = ldfrag(Bs, wn + j * 16 + mrow, s * 4 + q);
#pragma unroll
            for (int i = 0; i < 4; ++i)
#pragma unroll
                for (int j = 0; j < 4; ++j)
                    eacc[i][j] = __builtin_amdgcn_mfma_f32_16x16x32_bf16(
                        af[i], bfr[j], eacc[i][j], 0, 0, 0);
        }
        if ((it & 31) == 31) {
            const int exi = it >> 5;
#pragma unroll
            for (int i = 0; i < 4; ++i) {
                const int rl = wm + i * 16 + q * 4;
#pragma unroll
                for (int r = 0; r < 4; ++r) {
                    const float g = gs[(rl + r) * 16 + exi];
#pragma unroll
                    for (int j = 0; j < 4; ++j) {
                        acc[i][j][r] += g * eacc[i][j][r];
                        eacc[i][j][r] = 0.f;
                    }
                }
            }
        }
    }
    // epilogue: out = acc + sum_i gates_i * be_i
#pragma unroll
    for (int j = 0; j < 4; ++j) {
        const int cc = tile_n + wn + j * 16 + mrow;
        float bev[16];
#pragma unroll
        for (int ex2 = 0; ex2 < 16; ++ex2) bev[ex2] = be[(size_t)ex2 * ODIM + cc];
#pragma unroll
        for (int i = 0; i < 4; ++i) {
            const int rl = wm + i * 16 + q * 4;
#pragma unroll
            for (int r = 0; r < 4; ++r) {
                float s = acc[i][j][r];
#pragma unroll
                for (int ex2 = 0; ex2 < 16; ++ex2) s = fmaf(gs[(rl + r) * 16 + ex2], bev[ex2], s);
                out[(size_t)(tile_m + rl + r) * ODIM + cc] = s;
            }
        }
    }
}

extern "C" void kernel_launch(void* const* d_in, const int* in_sizes, int n_in,
                              void* d_out, int out_size, void* d_ws, size_t ws_size,
                              hipStream_t stream) {
    const float* x  = (const float*)d_in[0];
    const float* W1 = (const float*)d_in[1];
    const float* b1 = (const float*)d_in[2];
    const float* W2 = (const float*)d_in[3];
    const float* b2 = (const float*)d_in[4];
    const float* We = (const float*)d_in[5];
    const float* be = (const float*)d_in[6];
    float* out  = (float*)d_out;
    float* kout = out + (size_t)M_TOK * ODIM;

    char* ws = (char*)d_ws;
    ushort* x_hi   = (ushort*)(ws);                 //  33,554,432 B
    ushort* x_lo   = (ushort*)(ws + 33554432);      //  33,554,432 B
    ushort* w1t_hi = (ushort*)(ws + 67108864);      //  16,777,216 B
    ushort* w1t_lo = (ushort*)(ws + 83886080);      //  16,777,216 B
    float*  hbuf   = (float*) (ws + 100663296);     // 134,217,728 B
    ushort* weT    = (ushort*)(ws + 100663296);     // aliases hbuf (h dead before WeT built)
    float*  logits = (float*) (ws + 234881024);     //     524,288 B
    float*  gates  = (float*) (ws + 235405312);     //     524,288 B  (total ~225 MiB)

    split_x_kernel<<<16384, 256, 0, stream>>>(x, x_hi, x_lo);
    transpose_split_w1_kernel<<<2048, 256, 0, stream>>>(W1, w1t_hi, w1t_lo);
    gemm1_kernel<<<2048, 256, 0, stream>>>(x_hi, x_lo, w1t_hi, w1t_lo, b1, hbuf);
    gemm2_kernel<<<512, 256, 0, stream>>>(hbuf, W2, b2, logits);
    gates_kernel<<<32, 256, 0, stream>>>(logits, gates, kout);
    dim3 gwe(1024, 16);
    transpose_we_kernel<<<gwe, 256, 0, stream>>>(We, weT);
    moe_gemm_kernel<<<1024, 256, 0, stream>>>(x_hi, weT, gates, be, out);
}

// Round 2
// 1314.293 us; speedup vs baseline: 1.7228x; 1.7228x over previous
//
#include <hip/hip_runtime.h>
#include <stdint.h>

#define M_TOK 8192   // B*T
#define DDIM  2048
#define HDIM  4096
#define NEXP  16
#define ODIM  2048

typedef __attribute__((ext_vector_type(8))) __bf16 bf16x8;
typedef __attribute__((ext_vector_type(4))) float  f32x4;

__device__ __forceinline__ unsigned short f2bf(float f) {
    unsigned int u = __float_as_uint(f);
    unsigned int r = (u + 0x7FFFu + ((u >> 16) & 1u)) >> 16;   // RNE
    return (unsigned short)r;
}
__device__ __forceinline__ float bf2f(unsigned short s) {
    return __uint_as_float(((unsigned int)s) << 16);
}

// ---------------- preprocessing ----------------

__global__ void split_x_kernel(const float* __restrict__ x,
                               ushort* __restrict__ xh, ushort* __restrict__ xl) {
    size_t i = ((size_t)blockIdx.x * 256 + threadIdx.x) * 4;
    float4 v = *(const float4*)(x + i);
    float f[4] = {v.x, v.y, v.z, v.w};
    ushort hu[4], lu[4];
#pragma unroll
    for (int u = 0; u < 4; ++u) {
        hu[u] = f2bf(f[u]);
        lu[u] = f2bf(f[u] - bf2f(hu[u]));
    }
    *(ushort4*)(xh + i) = make_ushort4(hu[0], hu[1], hu[2], hu[3]);
    *(ushort4*)(xl + i) = make_ushort4(lu[0], lu[1], lu[2], lu[3]);
}

__global__ void transpose_split_w1_kernel(const float* __restrict__ W1,
                                          ushort* __restrict__ th, ushort* __restrict__ tl) {
    __shared__ float tile[64][65];
    int h0 = (blockIdx.x & 63) * 64;
    int d0 = (blockIdx.x >> 6) * 64;
    int r = threadIdx.x >> 4;
    int c = (threadIdx.x & 15) * 4;
#pragma unroll
    for (int rr = 0; rr < 4; ++rr) {
        int row = rr * 16 + r;
        float4 v = *(const float4*)(W1 + (size_t)(d0 + row) * HDIM + h0 + c);
        tile[row][c + 0] = v.x; tile[row][c + 1] = v.y;
        tile[row][c + 2] = v.z; tile[row][c + 3] = v.w;
    }
    __syncthreads();
#pragma unroll
    for (int rr = 0; rr < 4; ++rr) {
        int hrow = rr * 16 + r;
        ushort hu[4], lu[4];
#pragma unroll
        for (int u = 0; u < 4; ++u) {
            float f = tile[c + u][hrow];
            hu[u] = f2bf(f);
            lu[u] = f2bf(f - bf2f(hu[u]));
        }
        size_t o = (size_t)(h0 + hrow) * DDIM + d0 + c;
        *(ushort4*)(th + o) = make_ushort4(hu[0], hu[1], hu[2], hu[3]);
        *(ushort4*)(tl + o) = make_ushort4(lu[0], lu[1], lu[2], lu[3]);
    }
}

__global__ void transpose_we_kernel(const float* __restrict__ We, ushort* __restrict__ wt) {
    __shared__ float tile[64][65];
    int e = blockIdx.y;
    int o0 = (blockIdx.x & 31) * 64;
    int d0 = (blockIdx.x >> 5) * 64;
    const float* src = We + (size_t)e * DDIM * ODIM;
    ushort* dst = wt + (size_t)e * ODIM * DDIM;
    int r = threadIdx.x >> 4;
    int c = (threadIdx.x & 15) * 4;
#pragma unroll
    for (int rr = 0; rr < 4; ++rr) {
        int row = rr * 16 + r;
        float4 v = *(const float4*)(src + (size_t)(d0 + row) * ODIM + o0 + c);
        tile[row][c + 0] = v.x; tile[row][c + 1] = v.y;
        tile[row][c + 2] = v.z; tile[row][c + 3] = v.w;
    }
    __syncthreads();
#pragma unroll
    for (int rr = 0; rr < 4; ++rr) {
        int orow = rr * 16 + r;
        ushort hu[4];
#pragma unroll
        for (int u = 0; u < 4; ++u) hu[u] = f2bf(tile[c + u][orow]);
        *(ushort4*)(dst + (size_t)(o0 + orow) * DDIM + d0 + c) =
            make_ushort4(hu[0], hu[1], hu[2], hu[3]);
    }
}

// ---------------- GEMM core helpers (xor-swizzled LDS, 16B global_load_lds) ----------

__device__ __forceinline__ void stage_tile(const ushort* __restrict__ g0, int ld,
                                           ushort* lds0, int wave, int lane) {
#pragma unroll
    for (int j = 0; j < 4; ++j) {
        int L = wave * 256 + j * 64 + lane;
        int m = L >> 3;
        int kc = (L & 7) ^ (m & 7);
        const ushort* gp = g0 + (size_t)m * ld + kc * 8;
        ushort* lp = lds0 + (size_t)(wave * 256 + j * 64) * 8;
        __builtin_amdgcn_global_load_lds(
            (const __attribute__((address_space(1))) void*)gp,
            (__attribute__((address_space(3))) void*)lp, 16, 0, 0);
    }
}

__device__ __forceinline__ bf16x8 ldfrag(const ushort* lds0, int row, int kc) {
    return *(const bf16x8*)(lds0 + ((row << 3) + (kc ^ (row & 7))) * 8);
}

// Router GEMM1: h = relu([x_hi|x_lo|x_hi] @ [W1hi|W1hi|W1lo]^T + b1), K=3*2048
__global__ __launch_bounds__(256, 2) void gemm1_kernel(
    const ushort* __restrict__ xh, const ushort* __restrict__ xl,
    const ushort* __restrict__ wh, const ushort* __restrict__ wl,
    const float* __restrict__ b1, float* __restrict__ hout) {
    __shared__ ushort As[8192];
    __shared__ ushort Bs[8192];
    const int tile_m = (blockIdx.x & 63) << 7;
    const int tile_n = (blockIdx.x >> 6) << 7;
    const int tid = threadIdx.x;
    const int wave = tid >> 6, lane = tid & 63;
    const int q = lane >> 4, mrow = lane & 15;
    const int wm = (wave >> 1) << 6, wn = (wave & 1) << 6;
    f32x4 acc[4][4];
#pragma unroll
    for (int i = 0; i < 4; ++i)
#pragma unroll
        for (int j = 0; j < 4; ++j) acc[i][j] = {0.f, 0.f, 0.f, 0.f};

    for (int it = 0; it < 96; ++it) {
        const int phase = it >> 5;
        const ushort* Ab = (phase == 1) ? xl : xh;
        const ushort* Bb = (phase == 2) ? wl : wh;
        const int k0 = (it & 31) << 6;
        __syncthreads();
        stage_tile(Ab + (size_t)tile_m * DDIM + k0, DDIM, As, wave, lane);
        stage_tile(Bb + (size_t)tile_n * DDIM + k0, DDIM, Bs, wave, lane);
        __syncthreads();
#pragma unroll
        for (int s = 0; s < 2; ++s) {
            bf16x8 af[4], bfr[4];
#pragma unroll
            for (int i = 0; i < 4; ++i) af[i] = ldfrag(As, wm + i * 16 + mrow, s * 4 + q);
#pragma unroll
            for (int j = 0; j < 4; ++j) bfr[j] = ldfrag(Bs, wn + j * 16 + mrow, s * 4 + q);
#pragma unroll
            for (int i = 0; i < 4; ++i)
#pragma unroll
                for (int j = 0; j < 4; ++j)
                    acc[i][j] = __builtin_amdgcn_mfma_f32_16x16x32_bf16(
                        af[i], bfr[j], acc[i][j], 0, 0, 0);
        }
    }
#pragma unroll
    for (int i = 0; i < 4; ++i) {
        const int r0 = tile_m + wm + i * 16 + q * 4;
#pragma unroll
        for (int j = 0; j < 4; ++j) {
            const int cc = tile_n + wn + j * 16 + mrow;
            const float bb = b1[cc];
#pragma unroll
            for (int r = 0; r < 4; ++r) {
                float v = acc[i][j][r] + bb;
                hout[(size_t)(r0 + r) * HDIM + cc] = v > 0.f ? v : 0.f;
            }
        }
    }
}

// GEMM2 (fp32 vector): logits = h @ W2 + b2.
__global__ void gemm2_kernel(const float* __restrict__ h, const float* __restrict__ W2,
                             const float* __restrict__ b2, float* __restrict__ logits) {
    const int e = threadIdx.x & 15;
    const int t = blockIdx.x * 16 + (threadIdx.x >> 4);
    const float* hr = h + (size_t)t * HDIM;
    float acc = 0.f;
    for (int d = 0; d < HDIM; d += 8) {
#pragma unroll
        for (int u = 0; u < 8; ++u)
            acc = fmaf(hr[d + u], W2[(size_t)(d + u) * NEXP + e], acc);
    }
    logits[(size_t)t * NEXP + e] = acc + b2[e];
}

// softmax -> mask -> gates, k_per_token, and per-expert compacted token lists
__global__ void gates_kernel(const float* __restrict__ logits,
                             float* __restrict__ gates, float* __restrict__ kout,
                             int* __restrict__ cnt, int* __restrict__ list) {
    const int t = blockIdx.x * 256 + threadIdx.x;
    float l[16];
    const float4* lp = (const float4*)(logits + (size_t)t * 16);
#pragma unroll
    for (int i = 0; i < 4; ++i) {
        float4 v = lp[i];
        l[i * 4] = v.x; l[i * 4 + 1] = v.y; l[i * 4 + 2] = v.z; l[i * 4 + 3] = v.w;
    }
    float lmax = l[0];
#pragma unroll
    for (int i = 1; i < 16; ++i) lmax = fmaxf(lmax, l[i]);
    float p[16], S = 0.f;
#pragma unroll
    for (int i = 0; i < 16; ++i) { p[i] = expf(l[i] - lmax); S += p[i]; }
#pragma unroll
    for (int i = 0; i < 16; ++i) p[i] /= S;
    float pmax = p[0];
#pragma unroll
    for (int i = 1; i < 16; ++i) pmax = fmaxf(pmax, p[i]);
    const float thr = 0.5f * pmax;
    int k = 0;
    float g[16];
#pragma unroll
    for (int i = 0; i < 16; ++i) {
        bool m = p[i] >= thr;
        g[i] = m ? p[i] : 0.f;
        k += m ? 1 : 0;
        if (m) {
            int pos = atomicAdd(&cnt[i], 1);
            list[i * M_TOK + pos] = t;
        }
    }
    float4* gp = (float4*)(gates + (size_t)t * 16);
#pragma unroll
    for (int i = 0; i < 4; ++i)
        gp[i] = make_float4(g[i * 4], g[i * 4 + 1], g[i * 4 + 2], g[i * 4 + 3]);
    kout[t] = (float)k;
}

// out[t,:] = sum_e g[t,e] * be[e,:]  (base for the sparse atomic accumulate)
__global__ void init_out_kernel(const float* __restrict__ gates,
                                const float* __restrict__ be, float* __restrict__ out) {
    const int t = blockIdx.x;
    const int tid = threadIdx.x;
    __shared__ float g[16];
    if (tid < 16) g[tid] = gates[(size_t)t * 16 + tid];
    __syncthreads();
    const int c0 = tid * 8;
    float a[8] = {0.f, 0.f, 0.f, 0.f, 0.f, 0.f, 0.f, 0.f};
#pragma unroll
    for (int e = 0; e < 16; ++e) {
        float ge = g[e];
        if (ge != 0.f) {
            float4 v1 = *(const float4*)(be + (size_t)e * ODIM + c0);
            float4 v2 = *(const float4*)(be + (size_t)e * ODIM + c0 + 4);
            a[0] = fmaf(ge, v1.x, a[0]); a[1] = fmaf(ge, v1.y, a[1]);
            a[2] = fmaf(ge, v1.z, a[2]); a[3] = fmaf(ge, v1.w, a[3]);
            a[4] = fmaf(ge, v2.x, a[4]); a[5] = fmaf(ge, v2.y, a[5]);
            a[6] = fmaf(ge, v2.z, a[6]); a[7] = fmaf(ge, v2.w, a[7]);
        }
    }
    *(float4*)(out + (size_t)t * ODIM + c0)     = make_float4(a[0], a[1], a[2], a[3]);
    *(float4*)(out + (size_t)t * ODIM + c0 + 4) = make_float4(a[4], a[5], a[6], a[7]);
}

// Sparse expert GEMM: for expert e, gathered 128-token chunk, 128-col n-tile:
// out[tok,:] += g[tok,e] * (x[tok,:] @ We[e]).  K = 2048 (32 iters).
__global__ __launch_bounds__(256, 3) void moe_sparse_kernel(
    const ushort* __restrict__ xh, const ushort* __restrict__ weT,
    const float* __restrict__ gates, const int* __restrict__ cnt,
    const int* __restrict__ list, float* __restrict__ out) {
    const int bx = blockIdx.x;
    const int e = bx >> 10;
    const int chunk = (bx >> 4) & 63;
    const int ntile = bx & 15;
    const int ce = cnt[e];
    const int row0 = chunk << 7;
    if (row0 >= ce) return;
    const int rows = min(128, ce - row0);

    __shared__ ushort As[8192];
    __shared__ ushort Bs[8192];
    __shared__ int toks[128];
    __shared__ float gv[128];

    const int tid = threadIdx.x;
    if (tid < 128) {
        int t = list[e * M_TOK + row0 + min(tid, rows - 1)];
        toks[tid] = t;
        gv[tid] = gates[(size_t)t * NEXP + e];
    }
    __syncthreads();

    const int wave = tid >> 6, lane = tid & 63;
    const int q = lane >> 4, mrow = lane & 15;
    const int wm = (wave >> 1) << 6, wn = (wave & 1) << 6;

    // per-lane fixed staging pointers (A rows gathered; constant over K loop)
    const ushort* agp[4];
    const ushort* bgp[4];
    ushort* alp[4];
    ushort* blp[4];
    const ushort* wbase = weT + ((size_t)e * ODIM + (ntile << 7)) * DDIM;
#pragma unroll
    for (int j = 0; j < 4; ++j) {
        int L = wave * 256 + j * 64 + lane;
        int m = L >> 3;
        int kc = (L & 7) ^ (m & 7);
        agp[j] = xh + (size_t)toks[m] * DDIM + kc * 8;
        bgp[j] = wbase + (size_t)m * DDIM + kc * 8;
        alp[j] = As + (size_t)L * 8;
        blp[j] = Bs + (size_t)L * 8;
    }

    f32x4 acc[4][4];
#pragma unroll
    for (int i = 0; i < 4; ++i)
#pragma unroll
        for (int j = 0; j < 4; ++j) acc[i][j] = {0.f, 0.f, 0.f, 0.f};

    for (int it = 0; it < 32; ++it) {
        const int k0 = it << 6;
        __syncthreads();
#pragma unroll
        for (int j = 0; j < 4; ++j) {
            __builtin_amdgcn_global_load_lds(
                (const __attribute__((address_space(1))) void*)(agp[j] + k0),
                (__attribute__((address_space(3))) void*)alp[j], 16, 0, 0);
            __builtin_amdgcn_global_load_lds(
                (const __attribute__((address_space(1))) void*)(bgp[j] + k0),
                (__attribute__((address_space(3))) void*)blp[j], 16, 0, 0);
        }
        __syncthreads();
#pragma unroll
        for (int s = 0; s < 2; ++s) {
            bf16x8 af[4], bfr[4];
#pragma unroll
            for (int i = 0; i < 4; ++i) af[i] = ldfrag(As, wm + i * 16 + mrow, s * 4 + q);
#pragma unroll
            for (int j = 0; j < 4; ++j) bfr[j] = ldfrag(Bs, wn + j * 16 + mrow, s * 4 + q);
#pragma unroll
            for (int i = 0; i < 4; ++i)
#pragma unroll
                for (int j = 0; j < 4; ++j)
                    acc[i][j] = __builtin_amdgcn_mfma_f32_16x16x32_bf16(
                        af[i], bfr[j], acc[i][j], 0, 0, 0);
        }
    }

    // epilogue: atomic accumulate g * acc into out rows
#pragma unroll
    for (int i = 0; i < 4; ++i) {
        const int rl = wm + i * 16 + q * 4;
#pragma unroll
        for (int r = 0; r < 4; ++r) {
            const int lrow = rl + r;
            if (lrow < rows) {
                const int t = toks[lrow];
                const float g = gv[lrow];
                float* orow = out + (size_t)t * ODIM + (ntile << 7) + wn + mrow;
#pragma unroll
                for (int j = 0; j < 4; ++j)
                    atomicAdd(orow + j * 16, g * acc[i][j][r]);
            }
        }
    }
}

extern "C" void kernel_launch(void* const* d_in, const int* in_sizes, int n_in,
                              void* d_out, int out_size, void* d_ws, size_t ws_size,
                              hipStream_t stream) {
    const float* x  = (const float*)d_in[0];
    const float* W1 = (const float*)d_in[1];
    const float* b1 = (const float*)d_in[2];
    const float* W2 = (const float*)d_in[3];
    const float* b2 = (const float*)d_in[4];
    const float* We = (const float*)d_in[5];
    const float* be = (const float*)d_in[6];
    float* out  = (float*)d_out;
    float* kout = out + (size_t)M_TOK * ODIM;

    char* ws = (char*)d_ws;
    ushort* x_hi   = (ushort*)(ws);                 //  33,554,432 B
    ushort* x_lo   = (ushort*)(ws + 33554432);      //  33,554,432 B
    ushort* w1t_hi = (ushort*)(ws + 67108864);      //  16,777,216 B
    // w1t_lo region is dead after gemm1; cnt/list reuse it:
    ushort* w1t_lo = (ushort*)(ws + 83886080);      //  16,777,216 B
    int*    cnt    = (int*)   (ws + 83886080);      //  64 B (after gemm1)
    int*    list   = (int*)   (ws + 83887104);      //  512 KiB (after gemm1)
    float*  hbuf   = (float*) (ws + 100663296);     // 134,217,728 B
    ushort* weT    = (ushort*)(ws + 100663296);     // aliases hbuf (dead after gemm2)
    float*  logits = (float*) (ws + 234881024);     //  512 KiB
    float*  gates  = (float*) (ws + 235405312);     //  512 KiB

    split_x_kernel<<<16384, 256, 0, stream>>>(x, x_hi, x_lo);
    transpose_split_w1_kernel<<<2048, 256, 0, stream>>>(W1, w1t_hi, w1t_lo);
    gemm1_kernel<<<2048, 256, 0, stream>>>(x_hi, x_lo, w1t_hi, w1t_lo, b1, hbuf);
    gemm2_kernel<<<512, 256, 0, stream>>>(hbuf, W2, b2, logits);
    hipMemsetAsync(cnt, 0, 64, stream);
    gates_kernel<<<32, 256, 0, stream>>>(logits, gates, kout, cnt, list);
    dim3 gwe(1024, 16);
    transpose_we_kernel<<<gwe, 256, 0, stream>>>(We, weT);
    init_out_kernel<<<M_TOK, 256, 0, stream>>>(gates, be, out);
    moe_sparse_kernel<<<16384, 256, 0, stream>>>(x_hi, weT, gates, cnt, list, out);
}